// Round 2
// baseline (1204.881 us; speedup 1.0000x reference)
//
#include <hip/hip_runtime.h>
#include <hip/hip_bf16.h>

// WideEPMoE: route -> build per-expert token lists (stable order) ->
// GEMM1 (gather + w3/w1 + silu-mul fused) -> GEMM2 (+scale, atomicAdd combine).
// Dims fixed by the problem: T=16384, H=1024, I=512, E=64, C=1024, top_k=2.

constexpr int H    = 1024;
constexpr int IDIM = 512;
constexpr int NEXP = 64;
constexpr int CAP  = 1024;

typedef __attribute__((ext_vector_type(8))) short bf16x8;
typedef __attribute__((ext_vector_type(4))) float f32x4;
typedef __attribute__((ext_vector_type(8))) unsigned short u16x8;

#define LDK 56  // padded LDS row stride in bf16 elems (112B): conflict-free ds_read_b128

__device__ __forceinline__ unsigned short f2b(float f) {
  // round-to-nearest-even fp32 -> bf16 (inputs are finite; no NaN handling needed)
  unsigned u = __builtin_bit_cast(unsigned, f);
  u = (u + 0x7FFFu + ((u >> 16) & 1u)) >> 16;
  return (unsigned short)u;
}

__device__ __forceinline__ void cvt_store16(ushort* dst, const float* src) {
  float4 v0 = *(const float4*)(src);
  float4 v1 = *(const float4*)(src + 4);
  float4 v2 = *(const float4*)(src + 8);
  float4 v3 = *(const float4*)(src + 12);
  u16x8 p, q;
  p[0]=f2b(v0.x); p[1]=f2b(v0.y); p[2]=f2b(v0.z); p[3]=f2b(v0.w);
  p[4]=f2b(v1.x); p[5]=f2b(v1.y); p[6]=f2b(v1.z); p[7]=f2b(v1.w);
  q[0]=f2b(v2.x); q[1]=f2b(v2.y); q[2]=f2b(v2.z); q[3]=f2b(v2.w);
  q[4]=f2b(v3.x); q[5]=f2b(v3.y); q[6]=f2b(v3.z); q[7]=f2b(v3.w);
  *(u16x8*)dst = p;
  *(u16x8*)(dst + 8) = q;
}

__device__ __forceinline__ void zero_store16(ushort* dst) {
  u16x8 z = {0,0,0,0,0,0,0,0};
  *(u16x8*)dst = z;
  *(u16x8*)(dst + 8) = z;
}

// ---------------- kernel 1: routing (one wave per token; E==64==wave width) ---
__global__ void k_route(const float* __restrict__ logits, int* __restrict__ e0,
                        int* __restrict__ e1, float* __restrict__ s0,
                        float* __restrict__ s1, int T) {
  int gw = (blockIdx.x * blockDim.x + threadIdx.x) >> 6;
  int lane = threadIdx.x & 63;
  if (gw >= T) return;
  float l = logits[(size_t)gw * NEXP + lane];
  // argmax with lowest-index tiebreak (matches lax.top_k)
  float bl = l; int bi = lane;
  #pragma unroll
  for (int off = 32; off; off >>= 1) {
    float ol = __shfl_xor(bl, off);
    int   oi = __shfl_xor(bi, off);
    if (ol > bl || (ol == bl && oi < bi)) { bl = ol; bi = oi; }
  }
  float cl = (lane == bi) ? -1e30f : l; int ci = lane;
  #pragma unroll
  for (int off = 32; off; off >>= 1) {
    float ol = __shfl_xor(cl, off);
    int   oi = __shfl_xor(ci, off);
    if (ol > cl || (ol == cl && oi < ci)) { cl = ol; ci = oi; }
  }
  if (lane == 0) {
    // scales: softmax denominator cancels -> sigmoid of logit gap
    float p = 1.0f / (1.0f + __expf(cl - bl));
    e0[gw] = bi; e1[gw] = ci; s0[gw] = p; s1[gw] = 1.0f - p;
  }
}

// ------------- kernel 2: stable per-expert token lists (counting sort) -------
__global__ void k_build(const int* __restrict__ e0, const int* __restrict__ e1,
                        const float* __restrict__ s0, const float* __restrict__ s1,
                        int* __restrict__ tok_ids, float* __restrict__ scal,
                        int* __restrict__ counts, int T) {
  const int e = blockIdx.x;
  const int tid = threadIdx.x;
  const int lane = tid & 63, wv = tid >> 6;
  const int nw = blockDim.x >> 6;
  __shared__ int wcnt[16];
  int running = 0;
  for (int base = 0; base < T; base += blockDim.x) {
    int t = base + tid;
    bool f0 = (t < T) && (e0[t] == e);
    bool f1 = (t < T) && (e1[t] == e);
    bool f = f0 || f1;  // top-2 experts are distinct -> at most one slot matches
    unsigned long long m = __ballot(f);
    int wpos = __popcll(m & ((1ull << lane) - 1ull));
    if (lane == 0) wcnt[wv] = __popcll(m);
    __syncthreads();
    int pre = 0, tot = 0;
    for (int w = 0; w < nw; w++) { int c = wcnt[w]; if (w < wv) pre += c; tot += c; }
    if (f) {
      int pos = running + pre + wpos;  // stable: token-ascending within expert
      if (pos < CAP) {
        tok_ids[e * CAP + pos] = t;
        scal[e * CAP + pos] = f0 ? s0[t] : s1[t];
      }
    }
    running += tot;
    __syncthreads();
  }
  if (tid == 0) counts[e] = running < CAP ? running : CAP;
}

// --- kernel 3: gather + GEMM1 (A.B3^T and A.B1^T) + act = h3*silu(h1) -> bf16 ---
__launch_bounds__(256, 1)
__global__ void k_gemm1(const float* __restrict__ hidden, const float* __restrict__ w31,
                        const int* __restrict__ tok_ids, const int* __restrict__ counts,
                        ushort* __restrict__ act) {
  const int e = blockIdx.z;
  const int cnt = counts[e];
  const int m0 = blockIdx.y * 128;
  if (m0 >= cnt) return;
  const int n0 = blockIdx.x * 128;  // i-tile over IDIM

  __shared__ ushort At[128 * LDK];
  __shared__ ushort B3t[128 * LDK];
  __shared__ ushort B1t[128 * LDK];

  const int tid = threadIdx.x;
  const int lane = tid & 63;
  const int wv = tid >> 6;
  const int wm = wv >> 1, wn = wv & 1;

  const int srow = tid >> 1;        // staging row 0..127
  const int skh  = (tid & 1) * 16;  // k-half 0/16

  const float* aptr = nullptr;
  {
    int gm = m0 + srow;
    if (gm < cnt) {
      int tok = tok_ids[e * CAP + gm];
      aptr = hidden + (size_t)tok * H + skh;
    }
  }
  const float* b3p = w31 + ((size_t)e * (2 * IDIM) + (n0 + srow)) * H + skh;
  const float* b1p = b3p + (size_t)IDIM * H;

  ushort* aw  = &At[srow * LDK + skh];
  ushort* b3w = &B3t[srow * LDK + skh];
  ushort* b1w = &B1t[srow * LDK + skh];

  f32x4 acc3[4][4], acc1[4][4];
  const f32x4 zz = {0.f, 0.f, 0.f, 0.f};
  #pragma unroll
  for (int i = 0; i < 4; i++)
    #pragma unroll
    for (int j = 0; j < 4; j++) { acc3[i][j] = zz; acc1[i][j] = zz; }

  const int fr = lane & 15;
  const int kg = (lane >> 4) * 8;

  for (int k0 = 0; k0 < H; k0 += 32) {
    if (aptr) cvt_store16(aw, aptr + k0); else zero_store16(aw);
    cvt_store16(b3w, b3p + k0);
    cvt_store16(b1w, b1p + k0);
    __syncthreads();

    bf16x8 af[4], b3f[4], b1f[4];
    #pragma unroll
    for (int mf = 0; mf < 4; mf++)
      af[mf] = *(const bf16x8*)&At[(wm * 64 + mf * 16 + fr) * LDK + kg];
    #pragma unroll
    for (int nf = 0; nf < 4; nf++) {
      b3f[nf] = *(const bf16x8*)&B3t[(wn * 64 + nf * 16 + fr) * LDK + kg];
      b1f[nf] = *(const bf16x8*)&B1t[(wn * 64 + nf * 16 + fr) * LDK + kg];
    }
    #pragma unroll
    for (int mf = 0; mf < 4; mf++)
      #pragma unroll
      for (int nf = 0; nf < 4; nf++) {
        acc3[mf][nf] = __builtin_amdgcn_mfma_f32_16x16x32_bf16(af[mf], b3f[nf], acc3[mf][nf], 0, 0, 0);
        acc1[mf][nf] = __builtin_amdgcn_mfma_f32_16x16x32_bf16(af[mf], b1f[nf], acc1[mf][nf], 0, 0, 0);
      }
    __syncthreads();
  }

  // epilogue: C/D layout col=lane&15, row=(lane>>4)*4+r (m89-verified)
  const int fq = (lane >> 4) * 4;
  #pragma unroll
  for (int mf = 0; mf < 4; mf++) {
    const int gmb = m0 + wm * 64 + mf * 16 + fq;
    #pragma unroll
    for (int nf = 0; nf < 4; nf++) {
      const int col = n0 + wn * 64 + nf * 16 + fr;
      f32x4 v3 = acc3[mf][nf], v1 = acc1[mf][nf];
      #pragma unroll
      for (int r = 0; r < 4; r++) {
        int gm = gmb + r;
        if (gm < cnt) {
          float h1 = v1[r];
          float sg = h1 / (1.0f + __expf(-h1));  // silu
          act[((size_t)e * CAP + gm) * IDIM + col] = f2b(v3[r] * sg);
        }
      }
    }
  }
}

// ------ kernel 4: GEMM2 (act . w2^T), scale by gate, atomicAdd into y --------
__launch_bounds__(256, 1)
__global__ void k_gemm2(const ushort* __restrict__ act, const float* __restrict__ w2,
                        const int* __restrict__ tok_ids, const float* __restrict__ scal,
                        const int* __restrict__ counts, float* __restrict__ y) {
  const int e = blockIdx.z;
  const int cnt = counts[e];
  const int m0 = blockIdx.y * 128;
  if (m0 >= cnt) return;
  const int n0 = blockIdx.x * 128;  // h-tile over H

  __shared__ ushort At[128 * LDK];
  __shared__ ushort Bt[128 * LDK];

  const int tid = threadIdx.x;
  const int lane = tid & 63;
  const int wv = tid >> 6;
  const int wm = wv >> 1, wn = wv & 1;
  const int srow = tid >> 1;
  const int skh  = (tid & 1) * 16;

  const ushort* aptr = nullptr;
  if (m0 + srow < cnt) aptr = act + ((size_t)e * CAP + m0 + srow) * IDIM + skh;
  const float* bp = w2 + ((size_t)e * H + (n0 + srow)) * IDIM + skh;

  ushort* aw = &At[srow * LDK + skh];
  ushort* bw = &Bt[srow * LDK + skh];

  f32x4 acc[4][4];
  const f32x4 zz = {0.f, 0.f, 0.f, 0.f};
  #pragma unroll
  for (int i = 0; i < 4; i++)
    #pragma unroll
    for (int j = 0; j < 4; j++) acc[i][j] = zz;

  const int fr = lane & 15;
  const int kg = (lane >> 4) * 8;

  for (int k0 = 0; k0 < IDIM; k0 += 32) {
    if (aptr) {
      u16x8 q0 = *(const u16x8*)(aptr + k0);
      u16x8 q1 = *(const u16x8*)(aptr + k0 + 8);
      *(u16x8*)aw = q0;
      *(u16x8*)(aw + 8) = q1;
    } else zero_store16(aw);
    cvt_store16(bw, bp + k0);
    __syncthreads();

    bf16x8 af[4], bf[4];
    #pragma unroll
    for (int mf = 0; mf < 4; mf++)
      af[mf] = *(const bf16x8*)&At[(wm * 64 + mf * 16 + fr) * LDK + kg];
    #pragma unroll
    for (int nf = 0; nf < 4; nf++)
      bf[nf] = *(const bf16x8*)&Bt[(wn * 64 + nf * 16 + fr) * LDK + kg];
    #pragma unroll
    for (int mf = 0; mf < 4; mf++)
      #pragma unroll
      for (int nf = 0; nf < 4; nf++)
        acc[mf][nf] = __builtin_amdgcn_mfma_f32_16x16x32_bf16(af[mf], bf[nf], acc[mf][nf], 0, 0, 0);
    __syncthreads();
  }

  const int fq = (lane >> 4) * 4;
  #pragma unroll
  for (int mf = 0; mf < 4; mf++) {
    const int gmb = m0 + wm * 64 + mf * 16 + fq;
    int tk[4]; float sc[4];
    #pragma unroll
    for (int r = 0; r < 4; r++) {
      int gm = gmb + r;
      if (gm < cnt) { tk[r] = tok_ids[e * CAP + gm]; sc[r] = scal[e * CAP + gm]; }
      else tk[r] = -1;
    }
    #pragma unroll
    for (int nf = 0; nf < 4; nf++) {
      const int col = n0 + wn * 64 + nf * 16 + fr;
      f32x4 v = acc[mf][nf];
      #pragma unroll
      for (int r = 0; r < 4; r++)
        if (tk[r] >= 0) atomicAdd(&y[(size_t)tk[r] * H + col], v[r] * sc[r]);
    }
  }
}

extern "C" void kernel_launch(void* const* d_in, const int* in_sizes, int n_in,
                              void* d_out, int out_size, void* d_ws, size_t ws_size,
                              hipStream_t stream) {
  const float* hidden = (const float*)d_in[0];
  const float* logits = (const float*)d_in[1];
  const float* w31    = (const float*)d_in[2];
  const float* w2     = (const float*)d_in[3];
  // d_in[4] is top_k (==2 for this problem; routing kernel hardcodes top-2)
  const int T = in_sizes[1] / NEXP;
  float* y = (float*)d_out;

  // workspace layout (~64.8 MB total; ws is re-poisoned each call, and we
  // rewrite everything we read each call)
  char* w = (char*)d_ws;
  int*   e0      = (int*)w;   w += (size_t)T * 4;
  int*   e1      = (int*)w;   w += (size_t)T * 4;
  float* s0      = (float*)w; w += (size_t)T * 4;
  float* s1      = (float*)w; w += (size_t)T * 4;
  int*   tok_ids = (int*)w;   w += (size_t)NEXP * CAP * 4;
  float* scal    = (float*)w; w += (size_t)NEXP * CAP * 4;
  int*   counts  = (int*)w;   w += 256;
  ushort* act    = (ushort*)w;  // NEXP*CAP*IDIM*2 = 64 MB

  hipMemsetAsync(d_out, 0, (size_t)out_size * sizeof(float), stream);
  k_route<<<dim3((T + 3) / 4), 256, 0, stream>>>(logits, e0, e1, s0, s1, T);
  k_build<<<dim3(NEXP), 1024, 0, stream>>>(e0, e1, s0, s1, tok_ids, scal, counts, T);
  k_gemm1<<<dim3(IDIM / 128, CAP / 128, NEXP), 256, 0, stream>>>(hidden, w31, tok_ids, counts, act);
  k_gemm2<<<dim3(H / 128, CAP / 128, NEXP), 256, 0, stream>>>(act, w2, tok_ids, scal, counts, y);
}